// Round 14
// baseline (456.841 us; speedup 1.0000x reference)
//
#include <hip/hip_runtime.h>

typedef unsigned short u16;
typedef short bf16x8 __attribute__((ext_vector_type(8)));
typedef float f32x4 __attribute__((ext_vector_type(4)));

__device__ __forceinline__ float bf2f(u16 v){
  union { unsigned u; float f; } x; x.u = ((unsigned)v) << 16; return x.f;
}
__device__ __forceinline__ u16 f2bf(float f){
  union { float f; unsigned u; } x; x.f = f;
  unsigned u = x.u;
  u += 0x7fffu + ((u >> 16) & 1u);
  return (u16)(u >> 16);
}
__device__ __forceinline__ unsigned pk_bf16(float lo, float hi){
  unsigned r;
  asm("v_cvt_pk_bf16_f32 %0, %1, %2" : "=v"(r) : "v"(lo), "v"(hi));
  return r;
}
__device__ __forceinline__ u16 el4(ushort4 v, int r){ return r==0?v.x:r==1?v.y:r==2?v.z:v.w; }
__device__ __forceinline__ float elf4(float4 v, int r){ return r==0?v.x:r==1?v.y:r==2?v.z:v.w; }
__device__ __forceinline__ float sigm(float x){ return 1.f/(1.f+__expf(-x)); }
__device__ __forceinline__ float tanh_s(float x){ return 1.f - 2.f/(__expf(2.f*x)+1.f); }
__device__ __forceinline__ f32x4 mfma16(bf16x8 a, bf16x8 b, f32x4 c){
  return __builtin_amdgcn_mfma_f32_16x16x32_bf16(a, b, c, 0, 0, 0);
}
__device__ __forceinline__ void gl2lds16(const void* g, void* l){
  __builtin_amdgcn_global_load_lds(
      (const __attribute__((address_space(1))) unsigned int*)g,
      (__attribute__((address_space(3))) unsigned int*)l, 16, 0, 0);
}

// ---------------- prep: weights -> bf16 (+ layout splits) + bias fuse -------
__global__ void prep_w(const float* __restrict__ W_ih, const float* __restrict__ W_hh,
                       const float* __restrict__ Wph, const float* __restrict__ Woh,
                       const float* __restrict__ Wpm, const float* __restrict__ Wps,
                       const float* __restrict__ Wqm, const float* __restrict__ Wqs,
                       const float* __restrict__ Wg,  const float* __restrict__ bph,
                       const float* __restrict__ boh, const float* __restrict__ b_ih,
                       const float* __restrict__ b_hh,
                       u16* __restrict__ wsb, float* __restrict__ Woy,
                       float* __restrict__ bpq, float* __restrict__ bsum)
{
  int idx = blockIdx.x*256 + threadIdx.x;
  if (idx < 196608){ wsb[idx] = f2bf(W_ih[idx]); return; }
  if (idx < 393216){ wsb[idx] = f2bf(W_hh[idx-196608]); return; }
  if (idx < 524288){ int j = idx-393216; int row = j>>9, col = j&511;
    float v = (row<128) ? Wph[row*640+col] : Woh[(row-128)*642+col];
    wsb[idx] = f2bf(v); return; }
  if (idx < 540672){ int j = idx-524288; int row=j>>7, col=j&127; wsb[idx]=f2bf(Wph[row*640+512+col]); return; }
  if (idx < 557056){ int j = idx-540672; int row=j>>7, col=j&127; wsb[idx]=f2bf(Woh[row*642+514+col]); return; }
  if (idx < 573440){ wsb[idx]=f2bf(Wpm[idx-557056]); return; }
  if (idx < 589824){ wsb[idx]=f2bf(Wps[idx-573440]); return; }
  if (idx < 606208){ wsb[idx]=f2bf(Wqm[idx-589824]); return; }
  if (idx < 622592){ wsb[idx]=f2bf(Wqs[idx-606208]); return; }
  if (idx < 671744){ wsb[idx]=f2bf(Wg[idx-622592]); return; }
  if (idx < 672000){ int j = idx-671744; int row=j>>1; Woy[j] = Woh[row*642+512+(j&1)]; return; }
  if (idx < 672256){ int j = idx-672000; bpq[j] = (j<128) ? bph[j] : boh[j-128]; return; }
  if (idx < 673024){ int j = idx-672256; bsum[j] = b_ih[j] + (j < 512 ? b_hh[j] : 0.f); return; }
}

__global__ void prep_x(const float* __restrict__ x, u16* __restrict__ xbf){
  int i = blockIdx.x*256 + threadIdx.x;
  if (i >= 4194304) return;
  const float4* src = (const float4*)(x + (size_t)i*8);
  float4 a = src[0], b = src[1];
  uint4 o;
  o.x = pk_bf16(a.x, a.y);
  o.y = pk_bf16(a.z, a.w);
  o.z = pk_bf16(b.x, b.y);
  o.w = pk_bf16(b.z, b.w);
  ((uint4*)xbf)[i] = o;
}

// ---------------- counting sort of n_days, descending ----------------
__global__ void sort_days(const int* __restrict__ n_days, int* __restrict__ perm,
                          int* __restrict__ nd_s, int* __restrict__ cnt)
{
  __shared__ int hist[34];
  __shared__ int base[34];
  __shared__ int cursor[34];
  int tid = threadIdx.x;
  if (tid < 34) hist[tid] = 0;
  __syncthreads();
  for (int i = tid; i < 4096; i += 1024) atomicAdd(&hist[n_days[i]], 1);
  __syncthreads();
  if (tid == 0){
    int acc = 0;
    for (int v = 32; v >= 1; --v){ base[v] = acc; acc += hist[v]; }
    base[0] = acc;
  }
  __syncthreads();
  if (tid < 33) cursor[tid] = base[tid];
  if (tid < 32) cnt[tid] = base[tid];
  __syncthreads();
  for (int i = tid; i < 4096; i += 1024){
    int v = n_days[i];
    int pos = atomicAdd(&cursor[v], 1);
    perm[pos] = i;
    nd_s[pos] = v;
  }
}

// ---------------- GI GEMM: t-major sorted, tile-skip, coalesced epilogue ----
// __launch_bounds__(512,2): 128-reg cap -> acc[4][4]+frags fit with NO spill.
__global__ __launch_bounds__(512, 2) void gemm_gi(
  const u16* __restrict__ A, const u16* __restrict__ W,
  const float* __restrict__ bias, const int* __restrict__ perm,
  const int* __restrict__ cnt, u16* __restrict__ C)
{
  const int t  = blockIdx.x >> 5;
  const int rt = blockIdx.x & 31;
  if (rt*128 >= cnt[t]) return;
  const int n0 = blockIdx.y*256;
  const int tid = threadIdx.x;
  const int w = tid>>6, lane = tid&63, c = lane&15, g = lane>>4;
  const int wm = w>>2, wn = w&3;
  __shared__ __align__(16) char smem[49152];
  u16* abuf = (u16*)smem;
  u16* wbuf = (u16*)(smem + 16384);
  u16* clds = (u16*)smem;

  size_t asrc[2];
  #pragma unroll
  for (int i=0;i<2;++i){
    int p = (w*2+i)*64 + lane;
    int k8 = p>>7, row = p&127;
    asrc[i] = ((size_t)perm[rt*128 + row]*32 + t)*256 + k8*8;
  }
  size_t wsrc[4];
  #pragma unroll
  for (int i=0;i<4;++i){
    int p = (w*4+i)*64 + lane;
    int k8 = p>>8, row = p&255;
    wsrc[i] = (size_t)(n0+row)*256 + k8*8;
  }
  f32x4 acc[4][4];
  #pragma unroll
  for (int i=0;i<4;++i)
    #pragma unroll
    for (int j=0;j<4;++j) acc[i][j] = (f32x4){0.f,0.f,0.f,0.f};
  for (int kc=0; kc<4; ++kc){
    __syncthreads();
    #pragma unroll
    for (int i=0;i<2;++i) gl2lds16(A + asrc[i] + kc*64, &abuf[(w*2+i)*512]);
    #pragma unroll
    for (int i=0;i<4;++i) gl2lds16(W + wsrc[i] + kc*64, &wbuf[(w*4+i)*512]);
    __syncthreads();
    #pragma unroll
    for (int ks=0;ks<2;++ks){
      int k8 = ks*4 + g;
      bf16x8 a[4];
      #pragma unroll
      for (int mt=0;mt<4;++mt) a[mt] = *(const bf16x8*)&abuf[(k8*128 + wm*64 + mt*16 + c)*8];
      #pragma unroll
      for (int nt=0;nt<4;++nt){
        bf16x8 b = *(const bf16x8*)&wbuf[(k8*256 + wn*64 + nt*16 + c)*8];
        #pragma unroll
        for (int mt=0;mt<4;++mt)
          acc[mt][nt] = mfma16(a[mt], b, acc[mt][nt]);
      }
    }
  }
  __syncthreads();
  const size_t crow = (size_t)t*4096 + rt*128;
  #pragma unroll
  for (int nh=0; nh<2; ++nh){
    if ((wn>>1) == nh){
      #pragma unroll
      for (int nt=0;nt<4;++nt){
        int n = n0 + wn*64 + nt*16 + c;
        float bn = bias[n];
        int lc = (wn&1)*64 + nt*16 + c;
        #pragma unroll
        for (int mt=0;mt<4;++mt){
          int lr = wm*64 + mt*16 + g*4;
          #pragma unroll
          for (int r=0;r<4;++r)
            clds[(lr+r)*136 + lc] = f2bf(acc[mt][nt][r] + bn);
        }
      }
    }
    __syncthreads();
    #pragma unroll
    for (int p=0;p<4;++p){
      int idx = p*512 + tid;
      int row = idx>>4, ch = idx&15;
      *(uint4*)(C + (crow+row)*768 + n0 + nh*128 + ch*8)
        = *(const uint4*)&clds[row*136 + ch*8];
    }
    __syncthreads();
  }
}

// ---------------- HPQ GEMM (48KB LDS, 128-row tiles, no-spill bounds) -------
__global__ __launch_bounds__(512, 2) void gemm_hpq(
  const u16* __restrict__ A1, const u16* __restrict__ A2,
  const u16* __restrict__ W, const float* __restrict__ bias,
  const float* __restrict__ yt, const float* __restrict__ Woy,
  u16* __restrict__ C)
{
  const int m0 = blockIdx.x*128;
  const int tid = threadIdx.x;
  const int w = tid>>6, lane = tid&63, c = lane&15, g = lane>>4;
  const int wm = w>>2, wn = w&3;
  __shared__ __align__(16) char smem[49152];
  u16* abuf = (u16*)smem;
  u16* wbuf = (u16*)(smem + 16384);
  u16* clds = (u16*)smem;

  size_t asrc[2];
  #pragma unroll
  for (int i=0;i<2;++i){
    int p = (w*2+i)*64 + lane;
    int k8 = p>>7, row = p&127;
    asrc[i] = (size_t)(m0+row)*256 + k8*8;
  }
  size_t wsrc[4];
  #pragma unroll
  for (int i=0;i<4;++i){
    int p = (w*4+i)*64 + lane;
    int k8 = p>>8, row = p&255;
    wsrc[i] = (size_t)row*512 + k8*8;
  }
  f32x4 acc[4][4];
  #pragma unroll
  for (int i=0;i<4;++i)
    #pragma unroll
    for (int j=0;j<4;++j) acc[i][j] = (f32x4){0.f,0.f,0.f,0.f};
  for (int kc=0; kc<8; ++kc){
    __syncthreads();
    const u16* Ab = (kc < 4) ? A1 : A2;
    int ko = (kc & 3)*64;
    #pragma unroll
    for (int i=0;i<2;++i) gl2lds16(Ab + asrc[i] + ko, &abuf[(w*2+i)*512]);
    #pragma unroll
    for (int i=0;i<4;++i) gl2lds16(W + wsrc[i] + kc*64, &wbuf[(w*4+i)*512]);
    __syncthreads();
    #pragma unroll
    for (int ks=0;ks<2;++ks){
      int k8 = ks*4 + g;
      bf16x8 a[4];
      #pragma unroll
      for (int mt=0;mt<4;++mt) a[mt] = *(const bf16x8*)&abuf[(k8*128 + wm*64 + mt*16 + c)*8];
      #pragma unroll
      for (int nt=0;nt<4;++nt){
        bf16x8 b = *(const bf16x8*)&wbuf[(k8*256 + wn*64 + nt*16 + c)*8];
        #pragma unroll
        for (int mt=0;mt<4;++mt)
          acc[mt][nt] = mfma16(a[mt], b, acc[mt][nt]);
      }
    }
  }
  __syncthreads();
  #pragma unroll
  for (int nh=0; nh<2; ++nh){
    if ((wn>>1) == nh){
      #pragma unroll
      for (int nt=0;nt<4;++nt){
        int n = wn*64 + nt*16 + c;
        float bn = bias[n];
        float wy0 = 0.f, wy1 = 0.f;
        bool yfl = (n >= 128);
        if (yfl){ wy0 = Woy[(n-128)*2]; wy1 = Woy[(n-128)*2+1]; }
        int lc = (wn&1)*64 + nt*16 + c;
        #pragma unroll
        for (int mt=0;mt<4;++mt){
          int lr = wm*64 + mt*16 + g*4;
          #pragma unroll
          for (int r=0;r<4;++r){
            size_t m = (size_t)m0 + lr + r;
            float v = acc[mt][nt][r] + bn;
            if (yfl) v += yt[2*m]*wy0 + yt[2*m+1]*wy1;
            clds[(lr+r)*136 + lc] = f2bf(v);
          }
        }
      }
    }
    __syncthreads();
    #pragma unroll
    for (int p=0;p<4;++p){
      int idx = p*512 + tid;
      int row = idx>>4, ch = idx&15;
      *(uint4*)(C + (size_t)(m0+row)*256 + nh*128 + ch*8)
        = *(const uint4*)&clds[row*136 + ch*8];
    }
    __syncthreads();
  }
}

// ---------------- sequential GRU; R10 version (best measured: 141 us) -------
__global__ __launch_bounds__(1024, 4) void gru_seq(
  const u16* __restrict__ GI, const u16* __restrict__ Whh,
  const float* __restrict__ bhh, const int* __restrict__ perm,
  const int* __restrict__ nd_s, u16* __restrict__ hs)
{
  const int b0 = blockIdx.x*16;
  const int tid = threadIdx.x;
  const int w = tid>>6, lane = tid&63, c = lane&15, g = lane>>4;
  const int j0 = w*16 + g*4;
  __shared__ __align__(16) u16 hbuf[2][4096];     // 16KB
  __shared__ __align__(16) u16 gibuf[5][12288];   // 5 x 24KB = 120KB

  bf16x8 wa[3][8];
  #pragma unroll
  for (int gate=0; gate<3; ++gate)
    #pragma unroll
    for (int ks=0; ks<8; ++ks)
      wa[gate][ks] = *(const bf16x8*)&Whh[(size_t)(gate*256 + w*16 + c)*256 + ks*32 + g*8];

  const float4 bhn4 = *(const float4*)(bhh + 512 + j0);
  const int ndc   = nd_s[b0 + c];
  const int bound = nd_s[b0];
  const int ob    = perm[b0 + c];

  int so0, so1;
  { int pe = w*512 + lane*8; int row = pe/768, off = pe - row*768;
    so0 = (b0+row)*768 + (off ^ ((row&7)<<3)); }
  { int pe = (16+w)*512 + lane*8; int row = pe/768, off = pe - row*768;
    so1 = (b0+row)*768 + (off ^ ((row&7)<<3)); }
  const int rd0 = c*1536 + ((j0*2) ^ ((c&7)<<4));
  const int hroff = (g*16 + c)*16;
  const int hwoff = ((w*2 + (g>>1))*16 + c)*16 + (g&1)*8;
  u16* hsp = hs + (size_t)ob*8192 + j0;

  float hprev[4] = {0.f,0.f,0.f,0.f};
  if (tid < 512) ((uint4*)hbuf[0])[tid] = make_uint4(0,0,0,0);

  const size_t PL = 3145728;  // 4096*768
  #pragma unroll
  for (int p=0; p<4; ++p){
    int pp = (p < bound) ? p : bound-1;
    gl2lds16(GI + (size_t)pp*PL + so0, (char*)gibuf[p] + w*1024);
    if (w < 8) gl2lds16(GI + (size_t)pp*PL + so1, (char*)gibuf[p] + (16+w)*1024);
  }
  asm volatile("s_waitcnt vmcnt(0)" ::: "memory");
  __syncthreads();

  const u16* hr = hbuf[0];
  u16*       hw = hbuf[1];
  int cur = 0;
  #pragma unroll 1
  for (int t=0; t<bound; ++t){
    if (w < 8) asm volatile("s_waitcnt vmcnt(9)" ::: "memory");
    else       asm volatile("s_waitcnt vmcnt(6)" ::: "memory");
    __builtin_amdgcn_sched_barrier(0);
    const char* gib = (const char*)gibuf[cur];
    ushort4 gr_ = *(const ushort4*)(gib + rd0);
    ushort4 gu_ = *(const ushort4*)(gib + rd0 + 512);
    ushort4 gn_ = *(const ushort4*)(gib + rd0 + 1024);
    f32x4 aR = (f32x4){0.f,0.f,0.f,0.f};
    f32x4 aU = (f32x4){0.f,0.f,0.f,0.f};
    f32x4 aN = (f32x4){bhn4.x, bhn4.y, bhn4.z, bhn4.w};
    __builtin_amdgcn_s_setprio(1);
    #pragma unroll
    for (int ks=0; ks<8; ++ks){
      bf16x8 hf = *(const bf16x8*)((const char*)hr + hroff + ks*1024);
      aR = mfma16(wa[0][ks], hf, aR);
      aU = mfma16(wa[1][ks], hf, aU);
      aN = mfma16(wa[2][ks], hf, aN);
    }
    __builtin_amdgcn_s_setprio(0);
    {
      float h4[4];
      #pragma unroll
      for (int r=0; r<4; ++r){
        float rr = sigm(bf2f(el4(gr_,r)) + aR[r]);
        float uu = sigm(bf2f(el4(gu_,r)) + aU[r]);
        float nn = tanh_s(bf2f(el4(gn_,r)) + rr*aN[r]);
        float h = nn + uu*(hprev[r]-nn);
        hprev[r] = h;
        h4[r] = h;
      }
      uint2 hpk;
      hpk.x = pk_bf16(h4[0], h4[1]);
      hpk.y = pk_bf16(h4[2], h4[3]);
      *(uint2*)((char*)hw + hwoff) = hpk;
      uint2 hst = (t < ndc) ? hpk : make_uint2(0u,0u);
      *(uint2*)(hsp + t*256) = hst;
    }
    __builtin_amdgcn_sched_barrier(0);
    {
      int pf = (t+4 < bound) ? t+4 : bound-1;
      int nxt = cur >= 1 ? cur-1 : 4;   // (cur+4) mod 5
      gl2lds16(GI + (size_t)pf*PL + so0, (char*)gibuf[nxt] + w*1024);
      if (w < 8) gl2lds16(GI + (size_t)pf*PL + so1, (char*)gibuf[nxt] + (16+w)*1024);
    }
    asm volatile("s_waitcnt lgkmcnt(0)" ::: "memory");
    __builtin_amdgcn_sched_barrier(0);
    __builtin_amdgcn_s_barrier();
    __builtin_amdgcn_sched_barrier(0);
    { const u16* tmp = hr; hr = hw; hw = (u16*)tmp; }
    cur = (cur == 4) ? 0 : cur+1;
  }
  for (int t2 = bound; t2 < 32; ++t2)
    *(uint2*)(hsp + t2*256) = make_uint2(0u,0u);
}

// ---------------- sequential VAE scan; reg-prefetched HPQ/eps ---------------
__global__ __launch_bounds__(512) void vae_seq(
  const u16* __restrict__ HPQ, const float* __restrict__ z0,
  const float* __restrict__ eps, const int* __restrict__ n_days,
  const u16* __restrict__ Wm,
  const float* __restrict__ bpm, const float* __restrict__ bps,
  const float* __restrict__ bqm, const float* __restrict__ bqs,
  u16* __restrict__ zidx, float* __restrict__ out)
{
  const int b0 = blockIdx.x*16;
  const int tid = threadIdx.x, w = tid>>6, lane = tid&63, c = lane&15;
  const int g2 = lane>>4;
  const int j0 = w*16 + g2*4;
  __shared__ __align__(16) u16 zbuf[16*16*8];
  __shared__ __align__(16) u16 hzpb[16*16*8];
  __shared__ __align__(16) u16 hzqb[16*16*8];
  __shared__ float klb[32][16][8];

  bf16x8 wf[6][4];
  #pragma unroll
  for (int mat=0;mat<6;++mat)
    #pragma unroll
    for (int ks=0;ks<4;++ks)
      wf[mat][ks] = *(const bf16x8*)&Wm[mat*16384 + (w*16+c)*128 + ks*32 + g2*8];

  const float4 bpm4 = *(const float4*)(bpm + j0);
  const float4 bps4 = *(const float4*)(bps + j0);
  const float4 bqm4 = *(const float4*)(bqm + j0);
  const float4 bqs4 = *(const float4*)(bqs + j0);
  const int ndc = n_days[b0 + c];

  const int hroff = (g2*16 + c)*16;
  const int hwoff = ((w*2 + (g2>>1))*16 + c)*16 + (g2&1)*8;
  const u16*  hbp = HPQ + ((size_t)(b0+c)*32)*256 + j0;
  const float* ebp = eps + (size_t)(b0+c)*128 + j0;

  if (tid < 256){
    int k8 = tid>>4, row = tid&15;
    const float* zp = z0 + (size_t)(b0+row)*128 + k8*8;
    uint4 o;
    o.x = pk_bf16(zp[0], zp[1]);
    o.y = pk_bf16(zp[2], zp[3]);
    o.z = pk_bf16(zp[4], zp[5]);
    o.w = pk_bf16(zp[6], zp[7]);
    ((uint4*)zbuf)[tid] = o;
  }
  __syncthreads();

  ushort4 pA = *(const ushort4*)(hbp);
  ushort4 qA = *(const ushort4*)(hbp + 128);
  float4  eA = *(const float4*)(ebp);
  ushort4 pB = *(const ushort4*)(hbp + 256);
  ushort4 qB = *(const ushort4*)(hbp + 384);
  float4  eB = *(const float4*)(ebp + 524288);

  uint2 zsel = make_uint2(0u,0u);

  auto step = [&](ushort4& hp4, ushort4& hq4, float4& e4, int t){
    f32x4 accP = (f32x4){0,0,0,0}, accQ = (f32x4){0,0,0,0};
    #pragma unroll
    for (int ks=0;ks<4;++ks){
      bf16x8 zf = *(const bf16x8*)((const char*)zbuf + hroff + ks*1024);
      accP = mfma16(wf[0][ks], zf, accP);
      accQ = mfma16(wf[1][ks], zf, accQ);
    }
    float p4[4], q4[4];
    #pragma unroll
    for (int r=0;r<4;++r){
      p4[r] = tanh_s(bf2f(el4(hp4,r)) + accP[r]);
      q4[r] = tanh_s(bf2f(el4(hq4,r)) + accQ[r]);
    }
    uint2 ppk, qpk;
    ppk.x = pk_bf16(p4[0], p4[1]);  ppk.y = pk_bf16(p4[2], p4[3]);
    qpk.x = pk_bf16(q4[0], q4[1]);  qpk.y = pk_bf16(q4[2], q4[3]);
    *(uint2*)((char*)hzpb + hwoff) = ppk;
    *(uint2*)((char*)hzqb + hwoff) = qpk;
    asm volatile("s_waitcnt lgkmcnt(0)" ::: "memory");
    __builtin_amdgcn_sched_barrier(0);
    __builtin_amdgcn_s_barrier();
    __builtin_amdgcn_sched_barrier(0);
    f32x4 aMP=(f32x4){0,0,0,0}, aAP=(f32x4){0,0,0,0};
    f32x4 aMQ=(f32x4){0,0,0,0}, aAQ=(f32x4){0,0,0,0};
    #pragma unroll
    for (int ks=0;ks<4;++ks){
      bf16x8 pf = *(const bf16x8*)((const char*)hzpb + hroff + ks*1024);
      bf16x8 qf = *(const bf16x8*)((const char*)hzqb + hroff + ks*1024);
      aMP = mfma16(wf[2][ks], pf, aMP);
      aAP = mfma16(wf[3][ks], pf, aAP);
      aMQ = mfma16(wf[4][ks], qf, aMQ);
      aAQ = mfma16(wf[5][ks], qf, aAQ);
    }
    float kls = 0.f;
    float z4[4];
    #pragma unroll
    for (int r=0;r<4;++r){
      float mp = aMP[r]+elf4(bpm4,r);
      float ap = aAP[r]+elf4(bps4,r);
      float mq = aMQ[r]+elf4(bqm4,r);
      float aq = aAQ[r]+elf4(bqs4,r);
      float ev = elf4(e4,r);
      float z = mq + __expf(0.5f*aq)*ev;
      float d = mq - mp;
      kls += 0.5f*(ap-aq) + 0.5f*(__expf(aq)+d*d)*__expf(-ap) - 0.5f;
      z4[r] = z;
    }
    uint2 zpk;
    zpk.x = pk_bf16(z4[0], z4[1]);
    zpk.y = pk_bf16(z4[2], z4[3]);
    *(uint2*)((char*)zbuf + hwoff) = zpk;
    if (t == ndc-1) zsel = zpk;
    kls += __shfl_xor(kls, 16);
    kls += __shfl_xor(kls, 32);
    if (lane < 16) klb[t][c][w] = kls;
    if (t < 30){
      hp4 = *(const ushort4*)(hbp + (t+2)*256);
      hq4 = *(const ushort4*)(hbp + (t+2)*256 + 128);
      e4  = *(const float4*)(ebp + (size_t)(t+2)*524288);
    }
    asm volatile("s_waitcnt lgkmcnt(0)" ::: "memory");
    __builtin_amdgcn_sched_barrier(0);
    __builtin_amdgcn_s_barrier();
    __builtin_amdgcn_sched_barrier(0);
  };

  #pragma unroll 1
  for (int t=0; t<32; t+=2){
    step(pA, qA, eA, t);
    step(pB, qB, eB, t+1);
  }

  *(uint2*)(zidx + (size_t)(b0+c)*128 + j0) = zsel;
  {
    int t2 = tid>>4, c2 = tid&15;
    float s = 0.f;
    #pragma unroll
    for (int ww=0;ww<8;++ww) s += klb[t2][c2][ww];
    out[(size_t)(b0+c2)*162 + 130 + t2] = s;
  }
}

// ---------------- head: MFMA, 16 batch rows/block, Wg register-resident -----
__global__ __launch_bounds__(512) void head_k(
  const u16* __restrict__ hs, const u16* __restrict__ zidx,
  const int* __restrict__ n_days, const u16* __restrict__ Wgb,
  const float* __restrict__ bg, const float* __restrict__ Wy,
  const float* __restrict__ by, float* __restrict__ out)
{
  const int b0 = blockIdx.x*16;
  const int tid = threadIdx.x;
  const int w = tid>>6, lane = tid&63, c = lane&15, g = lane>>4;
  __shared__ __align__(16) u16 hzlds[48*16*8];   // 12KB
  __shared__ float glds[16*128];                  // 8KB
  __shared__ float ylds[16][2];

  for (int i=tid; i<768; i+=512){
    int row = i & 15, k8 = i >> 4;
    int b = b0 + row;
    uint4 v;
    if (k8 < 32){
      int idx = n_days[b] - 1;
      v = *(const uint4*)(hs + ((size_t)b*32 + idx)*256 + k8*8);
    } else {
      v = *(const uint4*)(zidx + (size_t)b*128 + (k8-32)*8);
    }
    *(uint4*)&hzlds[((size_t)k8*16 + row)*8] = v;
  }
  bf16x8 wf[12];
  #pragma unroll
  for (int ks=0;ks<12;++ks)
    wf[ks] = *(const bf16x8*)&Wgb[(size_t)(w*16 + c)*384 + ks*32 + g*8];
  const float4 bg4 = *(const float4*)(bg + w*16 + g*4);
  __syncthreads();

  f32x4 acc = (f32x4){0.f,0.f,0.f,0.f};
  #pragma unroll
  for (int ks=0;ks<12;++ks){
    bf16x8 hzf = *(const bf16x8*)&hzlds[((ks*4+g)*16 + c)*8];
    acc = mfma16(wf[ks], hzf, acc);
  }
  #pragma unroll
  for (int r=0;r<4;++r){
    float gv = tanh_s(acc[r] + elf4(bg4,r));
    glds[c*128 + w*16 + g*4 + r] = gv;
  }
  __syncthreads();
  {
    int row = w*2 + (lane>>5);
    int ll = lane & 31;
    float s0 = 0.f, s1 = 0.f;
    #pragma unroll
    for (int e=0;e<4;++e){
      float gv = glds[row*128 + ll*4 + e];
      s0 += gv * Wy[ll*4+e];
      s1 += gv * Wy[128 + ll*4+e];
    }
    s0 += __shfl_xor(s0,1); s0 += __shfl_xor(s0,2); s0 += __shfl_xor(s0,4);
    s0 += __shfl_xor(s0,8); s0 += __shfl_xor(s0,16);
    s1 += __shfl_xor(s1,1); s1 += __shfl_xor(s1,2); s1 += __shfl_xor(s1,4);
    s1 += __shfl_xor(s1,8); s1 += __shfl_xor(s1,16);
    if (ll == 0){
      float l0 = by[0] + s0, l1 = by[1] + s1;
      float mx = fmaxf(l0,l1);
      float e0 = __expf(l0-mx), e1 = __expf(l1-mx);
      float si = e0+e1;
      ylds[row][0] = e0/si;
      ylds[row][1] = e1/si;
    }
  }
  __syncthreads();
  for (int i=tid; i<2080; i+=512){
    int row = i/130, col = i - row*130;
    float v = (col < 128) ? glds[row*128 + col] : ylds[row][col-128];
    out[(size_t)(b0+row)*162 + col] = v;
  }
}

extern "C" void kernel_launch(void* const* d_in, const int* in_sizes, int n_in,
                              void* d_out, int out_size, void* d_ws, size_t ws_size,
                              hipStream_t stream)
{
  const float* x      = (const float*)d_in[0];
  const float* y_true = (const float*)d_in[1];
  const int*   n_days = (const int*)d_in[2];
  const float* z0     = (const float*)d_in[3];
  const float* eps    = (const float*)d_in[4];
  const float* W_ih   = (const float*)d_in[5];
  const float* W_hh   = (const float*)d_in[6];
  const float* b_ih   = (const float*)d_in[7];
  const float* b_hh   = (const float*)d_in[8];
  const float* Wph    = (const float*)d_in[9];
  const float* bph    = (const float*)d_in[10];
  const float* Woh    = (const float*)d_in[11];
  const float* boh    = (const float*)d_in[12];
  const float* Wpm    = (const float*)d_in[13];
  const float* bpm    = (const float*)d_in[14];
  const float* Wps    = (const float*)d_in[15];
  const float* bps    = (const float*)d_in[16];
  const float* Wqm    = (const float*)d_in[17];
  const float* bqm    = (const float*)d_in[18];
  const float* Wqs    = (const float*)d_in[19];
  const float* bqs    = (const float*)d_in[20];
  const float* Wg     = (const float*)d_in[21];
  const float* bg     = (const float*)d_in[22];
  const float* Wy     = (const float*)d_in[23];
  const float* by     = (const float*)d_in[24];
  (void)in_sizes; (void)n_in; (void)out_size; (void)ws_size;

  u16*   wsb = (u16*)d_ws;
  float* wsf = (float*)d_ws;
  int*   wsi = (int*)d_ws;
  u16* Wih_b = wsb + 0;
  u16* Whh_b = wsb + 196608;
  u16* Wc_b  = wsb + 393216;
  u16* Wz_b  = wsb + 524288;
  u16* Wg_b  = wsb + 622592;
  float* Woy  = wsf + 335872;
  float* bpq  = wsf + 336128;
  float* bsum = wsf + 336384;
  int* perm   = wsi + 337152;
  int* nd_s   = wsi + 341248;
  int* cnt    = wsi + 345344;
  u16* xbf   = wsb + 690752;
  u16* GI    = wsb + 34245184;
  u16* hsB   = wsb + 134908480;
  u16* HPQ   = wsb + 168462912;
  u16* zidx  = wsb + 202017344;

  hipLaunchKernelGGL(prep_w, dim3(2630), dim3(256), 0, stream,
                     W_ih, W_hh, Wph, Woh, Wpm, Wps, Wqm, Wqs, Wg, bph, boh,
                     b_ih, b_hh, wsb, Woy, bpq, bsum);
  hipLaunchKernelGGL(prep_x, dim3(16384), dim3(256), 0, stream, x, xbf);
  hipLaunchKernelGGL(sort_days, dim3(1), dim3(1024), 0, stream,
                     n_days, perm, nd_s, cnt);
  hipLaunchKernelGGL(gemm_gi, dim3(1024,3), dim3(512), 0, stream,
                     xbf, Wih_b, bsum, perm, cnt, GI);
  hipLaunchKernelGGL(gru_seq, dim3(256), dim3(1024), 0, stream,
                     GI, Whh_b, b_hh, perm, nd_s, hsB);
  hipLaunchKernelGGL(gemm_hpq, dim3(1024), dim3(512), 0, stream,
                     xbf, hsB, Wc_b, bpq, y_true, Woy, HPQ);
  hipLaunchKernelGGL(vae_seq, dim3(256), dim3(512), 0, stream,
                     HPQ, z0, eps, n_days, Wz_b, bpm, bps, bqm, bqs, zidx, (float*)d_out);
  hipLaunchKernelGGL(head_k, dim3(256), dim3(512), 0, stream,
                     hsB, zidx, n_days, Wg_b, bg, Wy, by, (float*)d_out);
}

// Round 15
// 439.395 us; speedup vs baseline: 1.0397x; 1.0397x over previous
//
#include <hip/hip_runtime.h>

typedef unsigned short u16;
typedef short bf16x8 __attribute__((ext_vector_type(8)));
typedef float f32x4 __attribute__((ext_vector_type(4)));

__device__ __forceinline__ float bf2f(u16 v){
  union { unsigned u; float f; } x; x.u = ((unsigned)v) << 16; return x.f;
}
__device__ __forceinline__ u16 f2bf(float f){
  union { float f; unsigned u; } x; x.f = f;
  unsigned u = x.u;
  u += 0x7fffu + ((u >> 16) & 1u);
  return (u16)(u >> 16);
}
__device__ __forceinline__ unsigned pk_bf16(float lo, float hi){
  unsigned r;
  asm("v_cvt_pk_bf16_f32 %0, %1, %2" : "=v"(r) : "v"(lo), "v"(hi));
  return r;
}
__device__ __forceinline__ u16 el4(ushort4 v, int r){ return r==0?v.x:r==1?v.y:r==2?v.z:v.w; }
__device__ __forceinline__ float elf4(float4 v, int r){ return r==0?v.x:r==1?v.y:r==2?v.z:v.w; }
__device__ __forceinline__ float sigm(float x){ return 1.f/(1.f+__expf(-x)); }
__device__ __forceinline__ float tanh_s(float x){ return 1.f - 2.f/(__expf(2.f*x)+1.f); }
__device__ __forceinline__ f32x4 mfma16(bf16x8 a, bf16x8 b, f32x4 c){
  return __builtin_amdgcn_mfma_f32_16x16x32_bf16(a, b, c, 0, 0, 0);
}
__device__ __forceinline__ void gl2lds16(const void* g, void* l){
  __builtin_amdgcn_global_load_lds(
      (const __attribute__((address_space(1))) unsigned int*)g,
      (__attribute__((address_space(3))) unsigned int*)l, 16, 0, 0);
}

// ---------------- prep: x->bf16, weights->bf16 (+ splits), bias fuse --------
__global__ void prep_all(const float* __restrict__ x,
                         const float* __restrict__ W_ih, const float* __restrict__ W_hh,
                         const float* __restrict__ Wph, const float* __restrict__ Woh,
                         const float* __restrict__ Wpm, const float* __restrict__ Wps,
                         const float* __restrict__ Wqm, const float* __restrict__ Wqs,
                         const float* __restrict__ Wg,  const float* __restrict__ bph,
                         const float* __restrict__ boh, const float* __restrict__ b_ih,
                         const float* __restrict__ b_hh,
                         u16* __restrict__ xbf, u16* __restrict__ wsb,
                         float* __restrict__ Woy, float* __restrict__ bpq,
                         float* __restrict__ bsum)
{
  if (blockIdx.x < 16384){
    int i = blockIdx.x*256 + threadIdx.x;
    const float4* src = (const float4*)(x + (size_t)i*8);
    float4 a = src[0], b = src[1];
    uint4 o;
    o.x = pk_bf16(a.x, a.y);
    o.y = pk_bf16(a.z, a.w);
    o.z = pk_bf16(b.x, b.y);
    o.w = pk_bf16(b.z, b.w);
    ((uint4*)xbf)[i] = o;
    return;
  }
  int idx = (blockIdx.x-16384)*256 + threadIdx.x;
  if (idx < 196608){ wsb[idx] = f2bf(W_ih[idx]); return; }
  if (idx < 393216){ wsb[idx] = f2bf(W_hh[idx-196608]); return; }
  if (idx < 524288){ int j = idx-393216; int row = j>>9, col = j&511;
    float v = (row<128) ? Wph[row*640+col] : Woh[(row-128)*642+col];
    wsb[idx] = f2bf(v); return; }
  if (idx < 540672){ int j = idx-524288; int row=j>>7, col=j&127; wsb[idx]=f2bf(Wph[row*640+512+col]); return; }
  if (idx < 557056){ int j = idx-540672; int row=j>>7, col=j&127; wsb[idx]=f2bf(Woh[row*642+514+col]); return; }
  if (idx < 573440){ wsb[idx]=f2bf(Wpm[idx-557056]); return; }
  if (idx < 589824){ wsb[idx]=f2bf(Wps[idx-573440]); return; }
  if (idx < 606208){ wsb[idx]=f2bf(Wqm[idx-589824]); return; }
  if (idx < 622592){ wsb[idx]=f2bf(Wqs[idx-606208]); return; }
  if (idx < 671744){ wsb[idx]=f2bf(Wg[idx-622592]); return; }
  if (idx < 672000){ int j = idx-671744; int row=j>>1; Woy[j] = Woh[row*642+512+(j&1)]; return; }
  if (idx < 672256){ int j = idx-672000; bpq[j] = (j<128) ? bph[j] : boh[j-128]; return; }
  if (idx < 673024){ int j = idx-672256; bsum[j] = b_ih[j] + (j < 512 ? b_hh[j] : 0.f); return; }
}

// ---------------- counting sort of n_days, descending ----------------
__global__ void sort_days(const int* __restrict__ n_days, int* __restrict__ perm,
                          int* __restrict__ nd_s, int* __restrict__ cnt)
{
  __shared__ int hist[34];
  __shared__ int base[34];
  __shared__ int cursor[34];
  int tid = threadIdx.x;
  if (tid < 34) hist[tid] = 0;
  __syncthreads();
  for (int i = tid; i < 4096; i += 1024) atomicAdd(&hist[n_days[i]], 1);
  __syncthreads();
  if (tid == 0){
    int acc = 0;
    for (int v = 32; v >= 1; --v){ base[v] = acc; acc += hist[v]; }
    base[0] = acc;
  }
  __syncthreads();
  if (tid < 33) cursor[tid] = base[tid];
  if (tid < 32) cnt[tid] = base[tid];
  __syncthreads();
  for (int i = tid; i < 4096; i += 1024){
    int v = n_days[i];
    int pos = atomicAdd(&cursor[v], 1);
    perm[pos] = i;
    nd_s[pos] = v;
  }
}

// ---------------- GI GEMM: t-major sorted, tile-skip, coalesced epilogue ----
__global__ __launch_bounds__(512, 4) void gemm_gi(
  const u16* __restrict__ A, const u16* __restrict__ W,
  const float* __restrict__ bias, const int* __restrict__ perm,
  const int* __restrict__ cnt, u16* __restrict__ C)
{
  const int t  = blockIdx.x >> 5;
  const int rt = blockIdx.x & 31;
  if (rt*128 >= cnt[t]) return;
  const int n0 = blockIdx.y*256;
  const int tid = threadIdx.x;
  const int w = tid>>6, lane = tid&63, c = lane&15, g = lane>>4;
  const int wm = w>>2, wn = w&3;
  __shared__ __align__(16) char smem[49152];
  u16* abuf = (u16*)smem;
  u16* wbuf = (u16*)(smem + 16384);
  u16* clds = (u16*)smem;

  size_t asrc[2];
  #pragma unroll
  for (int i=0;i<2;++i){
    int p = (w*2+i)*64 + lane;
    int k8 = p>>7, row = p&127;
    asrc[i] = ((size_t)perm[rt*128 + row]*32 + t)*256 + k8*8;
  }
  size_t wsrc[4];
  #pragma unroll
  for (int i=0;i<4;++i){
    int p = (w*4+i)*64 + lane;
    int k8 = p>>8, row = p&255;
    wsrc[i] = (size_t)(n0+row)*256 + k8*8;
  }
  f32x4 acc[4][4];
  #pragma unroll
  for (int i=0;i<4;++i)
    #pragma unroll
    for (int j=0;j<4;++j) acc[i][j] = (f32x4){0.f,0.f,0.f,0.f};
  for (int kc=0; kc<4; ++kc){
    __syncthreads();
    #pragma unroll
    for (int i=0;i<2;++i) gl2lds16(A + asrc[i] + kc*64, &abuf[(w*2+i)*512]);
    #pragma unroll
    for (int i=0;i<4;++i) gl2lds16(W + wsrc[i] + kc*64, &wbuf[(w*4+i)*512]);
    __syncthreads();
    #pragma unroll
    for (int ks=0;ks<2;++ks){
      int k8 = ks*4 + g;
      bf16x8 a[4];
      #pragma unroll
      for (int mt=0;mt<4;++mt) a[mt] = *(const bf16x8*)&abuf[(k8*128 + wm*64 + mt*16 + c)*8];
      #pragma unroll
      for (int nt=0;nt<4;++nt){
        bf16x8 b = *(const bf16x8*)&wbuf[(k8*256 + wn*64 + nt*16 + c)*8];
        #pragma unroll
        for (int mt=0;mt<4;++mt)
          acc[mt][nt] = mfma16(a[mt], b, acc[mt][nt]);
      }
    }
  }
  __syncthreads();
  const size_t crow = (size_t)t*4096 + rt*128;
  #pragma unroll
  for (int nh=0; nh<2; ++nh){
    if ((wn>>1) == nh){
      #pragma unroll
      for (int nt=0;nt<4;++nt){
        int n = n0 + wn*64 + nt*16 + c;
        float bn = bias[n];
        int lc = (wn&1)*64 + nt*16 + c;
        #pragma unroll
        for (int mt=0;mt<4;++mt){
          int lr = wm*64 + mt*16 + g*4;
          #pragma unroll
          for (int r=0;r<4;++r)
            clds[(lr+r)*136 + lc] = f2bf(acc[mt][nt][r] + bn);
        }
      }
    }
    __syncthreads();
    #pragma unroll
    for (int p=0;p<4;++p){
      int idx = p*512 + tid;
      int row = idx>>4, ch = idx&15;
      *(uint4*)(C + (crow+row)*768 + n0 + nh*128 + ch*8)
        = *(const uint4*)&clds[row*136 + ch*8];
    }
    __syncthreads();
  }
}

// ---------------- HPQ GEMM (48KB LDS, 128-row tiles) ----------
__global__ __launch_bounds__(512, 4) void gemm_hpq(
  const u16* __restrict__ A1, const u16* __restrict__ A2,
  const u16* __restrict__ W, const float* __restrict__ bias,
  const float* __restrict__ yt, const float* __restrict__ Woy,
  u16* __restrict__ C)
{
  const int m0 = blockIdx.x*128;
  const int tid = threadIdx.x;
  const int w = tid>>6, lane = tid&63, c = lane&15, g = lane>>4;
  const int wm = w>>2, wn = w&3;
  __shared__ __align__(16) char smem[49152];
  u16* abuf = (u16*)smem;
  u16* wbuf = (u16*)(smem + 16384);
  u16* clds = (u16*)smem;

  size_t asrc[2];
  #pragma unroll
  for (int i=0;i<2;++i){
    int p = (w*2+i)*64 + lane;
    int k8 = p>>7, row = p&127;
    asrc[i] = (size_t)(m0+row)*256 + k8*8;
  }
  size_t wsrc[4];
  #pragma unroll
  for (int i=0;i<4;++i){
    int p = (w*4+i)*64 + lane;
    int k8 = p>>8, row = p&255;
    wsrc[i] = (size_t)row*512 + k8*8;
  }
  f32x4 acc[4][4];
  #pragma unroll
  for (int i=0;i<4;++i)
    #pragma unroll
    for (int j=0;j<4;++j) acc[i][j] = (f32x4){0.f,0.f,0.f,0.f};
  for (int kc=0; kc<8; ++kc){
    __syncthreads();
    const u16* Ab = (kc < 4) ? A1 : A2;
    int ko = (kc & 3)*64;
    #pragma unroll
    for (int i=0;i<2;++i) gl2lds16(Ab + asrc[i] + ko, &abuf[(w*2+i)*512]);
    #pragma unroll
    for (int i=0;i<4;++i) gl2lds16(W + wsrc[i] + kc*64, &wbuf[(w*4+i)*512]);
    __syncthreads();
    #pragma unroll
    for (int ks=0;ks<2;++ks){
      int k8 = ks*4 + g;
      bf16x8 a[4];
      #pragma unroll
      for (int mt=0;mt<4;++mt) a[mt] = *(const bf16x8*)&abuf[(k8*128 + wm*64 + mt*16 + c)*8];
      #pragma unroll
      for (int nt=0;nt<4;++nt){
        bf16x8 b = *(const bf16x8*)&wbuf[(k8*256 + wn*64 + nt*16 + c)*8];
        #pragma unroll
        for (int mt=0;mt<4;++mt)
          acc[mt][nt] = mfma16(a[mt], b, acc[mt][nt]);
      }
    }
  }
  __syncthreads();
  #pragma unroll
  for (int nh=0; nh<2; ++nh){
    if ((wn>>1) == nh){
      #pragma unroll
      for (int nt=0;nt<4;++nt){
        int n = wn*64 + nt*16 + c;
        float bn = bias[n];
        float wy0 = 0.f, wy1 = 0.f;
        bool yfl = (n >= 128);
        if (yfl){ wy0 = Woy[(n-128)*2]; wy1 = Woy[(n-128)*2+1]; }
        int lc = (wn&1)*64 + nt*16 + c;
        #pragma unroll
        for (int mt=0;mt<4;++mt){
          int lr = wm*64 + mt*16 + g*4;
          #pragma unroll
          for (int r=0;r<4;++r){
            size_t m = (size_t)m0 + lr + r;
            float v = acc[mt][nt][r] + bn;
            if (yfl) v += yt[2*m]*wy0 + yt[2*m+1]*wy1;
            clds[(lr+r)*136 + lc] = f2bf(v);
          }
        }
      }
    }
    __syncthreads();
    #pragma unroll
    for (int p=0;p<4;++p){
      int idx = p*512 + tid;
      int row = idx>>4, ch = idx&15;
      *(uint4*)(C + (size_t)(m0+row)*256 + nh*128 + ch*8)
        = *(const uint4*)&clds[row*136 + ch*8];
    }
    __syncthreads();
  }
}

// ---------------- sequential GRU; R10 version (best measured: 141 us) -------
__global__ __launch_bounds__(1024, 4) void gru_seq(
  const u16* __restrict__ GI, const u16* __restrict__ Whh,
  const float* __restrict__ bhh, const int* __restrict__ perm,
  const int* __restrict__ nd_s, u16* __restrict__ hs)
{
  const int b0 = blockIdx.x*16;
  const int tid = threadIdx.x;
  const int w = tid>>6, lane = tid&63, c = lane&15, g = lane>>4;
  const int j0 = w*16 + g*4;
  __shared__ __align__(16) u16 hbuf[2][4096];     // 16KB
  __shared__ __align__(16) u16 gibuf[5][12288];   // 5 x 24KB = 120KB

  bf16x8 wa[3][8];
  #pragma unroll
  for (int gate=0; gate<3; ++gate)
    #pragma unroll
    for (int ks=0; ks<8; ++ks)
      wa[gate][ks] = *(const bf16x8*)&Whh[(size_t)(gate*256 + w*16 + c)*256 + ks*32 + g*8];

  const float4 bhn4 = *(const float4*)(bhh + 512 + j0);
  const int ndc   = nd_s[b0 + c];
  const int bound = nd_s[b0];
  const int ob    = perm[b0 + c];

  int so0, so1;
  { int pe = w*512 + lane*8; int row = pe/768, off = pe - row*768;
    so0 = (b0+row)*768 + (off ^ ((row&7)<<3)); }
  { int pe = (16+w)*512 + lane*8; int row = pe/768, off = pe - row*768;
    so1 = (b0+row)*768 + (off ^ ((row&7)<<3)); }
  const int rd0 = c*1536 + ((j0*2) ^ ((c&7)<<4));
  const int hroff = (g*16 + c)*16;
  const int hwoff = ((w*2 + (g>>1))*16 + c)*16 + (g&1)*8;
  u16* hsp = hs + (size_t)ob*8192 + j0;

  float hprev[4] = {0.f,0.f,0.f,0.f};
  if (tid < 512) ((uint4*)hbuf[0])[tid] = make_uint4(0,0,0,0);

  const size_t PL = 3145728;  // 4096*768
  #pragma unroll
  for (int p=0; p<4; ++p){
    int pp = (p < bound) ? p : bound-1;
    gl2lds16(GI + (size_t)pp*PL + so0, (char*)gibuf[p] + w*1024);
    if (w < 8) gl2lds16(GI + (size_t)pp*PL + so1, (char*)gibuf[p] + (16+w)*1024);
  }
  asm volatile("s_waitcnt vmcnt(0)" ::: "memory");
  __syncthreads();

  const u16* hr = hbuf[0];
  u16*       hw = hbuf[1];
  int cur = 0;
  #pragma unroll 1
  for (int t=0; t<bound; ++t){
    if (w < 8) asm volatile("s_waitcnt vmcnt(9)" ::: "memory");
    else       asm volatile("s_waitcnt vmcnt(6)" ::: "memory");
    __builtin_amdgcn_sched_barrier(0);
    const char* gib = (const char*)gibuf[cur];
    ushort4 gr_ = *(const ushort4*)(gib + rd0);
    ushort4 gu_ = *(const ushort4*)(gib + rd0 + 512);
    ushort4 gn_ = *(const ushort4*)(gib + rd0 + 1024);
    f32x4 aR = (f32x4){0.f,0.f,0.f,0.f};
    f32x4 aU = (f32x4){0.f,0.f,0.f,0.f};
    f32x4 aN = (f32x4){bhn4.x, bhn4.y, bhn4.z, bhn4.w};
    __builtin_amdgcn_s_setprio(1);
    #pragma unroll
    for (int ks=0; ks<8; ++ks){
      bf16x8 hf = *(const bf16x8*)((const char*)hr + hroff + ks*1024);
      aR = mfma16(wa[0][ks], hf, aR);
      aU = mfma16(wa[1][ks], hf, aU);
      aN = mfma16(wa[2][ks], hf, aN);
    }
    __builtin_amdgcn_s_setprio(0);
    {
      float h4[4];
      #pragma unroll
      for (int r=0; r<4; ++r){
        float rr = sigm(bf2f(el4(gr_,r)) + aR[r]);
        float uu = sigm(bf2f(el4(gu_,r)) + aU[r]);
        float nn = tanh_s(bf2f(el4(gn_,r)) + rr*aN[r]);
        float h = nn + uu*(hprev[r]-nn);
        hprev[r] = h;
        h4[r] = h;
      }
      uint2 hpk;
      hpk.x = pk_bf16(h4[0], h4[1]);
      hpk.y = pk_bf16(h4[2], h4[3]);
      *(uint2*)((char*)hw + hwoff) = hpk;
      uint2 hst = (t < ndc) ? hpk : make_uint2(0u,0u);
      *(uint2*)(hsp + t*256) = hst;
    }
    __builtin_amdgcn_sched_barrier(0);
    {
      int pf = (t+4 < bound) ? t+4 : bound-1;
      int nxt = cur >= 1 ? cur-1 : 4;   // (cur+4) mod 5
      gl2lds16(GI + (size_t)pf*PL + so0, (char*)gibuf[nxt] + w*1024);
      if (w < 8) gl2lds16(GI + (size_t)pf*PL + so1, (char*)gibuf[nxt] + (16+w)*1024);
    }
    asm volatile("s_waitcnt lgkmcnt(0)" ::: "memory");
    __builtin_amdgcn_sched_barrier(0);
    __builtin_amdgcn_s_barrier();
    __builtin_amdgcn_sched_barrier(0);
    { const u16* tmp = hr; hr = hw; hw = (u16*)tmp; }
    cur = (cur == 4) ? 0 : cur+1;
  }
  for (int t2 = bound; t2 < 32; ++t2)
    *(uint2*)(hsp + t2*256) = make_uint2(0u,0u);
}

// ---------------- sequential VAE scan + fused output head -------------------
// 256 blocks x 512 threads, 16 batch rows/block. After the t-loop the block
// already holds z(idx) in registers (zsel) -> head computed in-place.
__global__ __launch_bounds__(512) void vae_seq(
  const u16* __restrict__ HPQ, const float* __restrict__ z0,
  const float* __restrict__ eps, const int* __restrict__ n_days,
  const u16* __restrict__ Wm,
  const float* __restrict__ bpm, const float* __restrict__ bps,
  const float* __restrict__ bqm, const float* __restrict__ bqs,
  const u16* __restrict__ hs, const u16* __restrict__ Wgb,
  const float* __restrict__ bg, const float* __restrict__ Wy,
  const float* __restrict__ by, float* __restrict__ out)
{
  const int b0 = blockIdx.x*16;
  const int tid = threadIdx.x, w = tid>>6, lane = tid&63, c = lane&15;
  const int g2 = lane>>4;
  const int j0 = w*16 + g2*4;
  __shared__ __align__(16) u16 zbuf[16*16*8];
  __shared__ __align__(16) u16 hzpb[16*16*8];
  __shared__ __align__(16) u16 hzqb[16*16*8];
  __shared__ float klb[32][16][8];
  __shared__ __align__(16) u16 hzlds[48*16*8];   // 12KB (head input)
  __shared__ float glds[16*128];                  // 8KB
  __shared__ float ylds[16][2];

  bf16x8 wf[6][4];
  #pragma unroll
  for (int mat=0;mat<6;++mat)
    #pragma unroll
    for (int ks=0;ks<4;++ks)
      wf[mat][ks] = *(const bf16x8*)&Wm[mat*16384 + (w*16+c)*128 + ks*32 + g2*8];

  const float4 bpm4 = *(const float4*)(bpm + j0);
  const float4 bps4 = *(const float4*)(bps + j0);
  const float4 bqm4 = *(const float4*)(bqm + j0);
  const float4 bqs4 = *(const float4*)(bqs + j0);
  const int ndc = n_days[b0 + c];

  const int hroff = (g2*16 + c)*16;
  const int hwoff = ((w*2 + (g2>>1))*16 + c)*16 + (g2&1)*8;
  const u16*  hbp = HPQ + ((size_t)(b0+c)*32)*256 + j0;
  const float* ebp = eps + (size_t)(b0+c)*128 + j0;

  if (tid < 256){
    int k8 = tid>>4, row = tid&15;
    const float* zp = z0 + (size_t)(b0+row)*128 + k8*8;
    uint4 o;
    o.x = pk_bf16(zp[0], zp[1]);
    o.y = pk_bf16(zp[2], zp[3]);
    o.z = pk_bf16(zp[4], zp[5]);
    o.w = pk_bf16(zp[6], zp[7]);
    ((uint4*)zbuf)[tid] = o;
  }
  __syncthreads();

  ushort4 pA = *(const ushort4*)(hbp);
  ushort4 qA = *(const ushort4*)(hbp + 128);
  float4  eA = *(const float4*)(ebp);
  ushort4 pB = *(const ushort4*)(hbp + 256);
  ushort4 qB = *(const ushort4*)(hbp + 384);
  float4  eB = *(const float4*)(ebp + 524288);

  uint2 zsel = make_uint2(0u,0u);

  auto step = [&](ushort4& hp4, ushort4& hq4, float4& e4, int t){
    f32x4 accP = (f32x4){0,0,0,0}, accQ = (f32x4){0,0,0,0};
    #pragma unroll
    for (int ks=0;ks<4;++ks){
      bf16x8 zf = *(const bf16x8*)((const char*)zbuf + hroff + ks*1024);
      accP = mfma16(wf[0][ks], zf, accP);
      accQ = mfma16(wf[1][ks], zf, accQ);
    }
    float p4[4], q4[4];
    #pragma unroll
    for (int r=0;r<4;++r){
      p4[r] = tanh_s(bf2f(el4(hp4,r)) + accP[r]);
      q4[r] = tanh_s(bf2f(el4(hq4,r)) + accQ[r]);
    }
    uint2 ppk, qpk;
    ppk.x = pk_bf16(p4[0], p4[1]);  ppk.y = pk_bf16(p4[2], p4[3]);
    qpk.x = pk_bf16(q4[0], q4[1]);  qpk.y = pk_bf16(q4[2], q4[3]);
    *(uint2*)((char*)hzpb + hwoff) = ppk;
    *(uint2*)((char*)hzqb + hwoff) = qpk;
    asm volatile("s_waitcnt lgkmcnt(0)" ::: "memory");
    __builtin_amdgcn_sched_barrier(0);
    __builtin_amdgcn_s_barrier();
    __builtin_amdgcn_sched_barrier(0);
    f32x4 aMP=(f32x4){0,0,0,0}, aAP=(f32x4){0,0,0,0};
    f32x4 aMQ=(f32x4){0,0,0,0}, aAQ=(f32x4){0,0,0,0};
    #pragma unroll
    for (int ks=0;ks<4;++ks){
      bf16x8 pf = *(const bf16x8*)((const char*)hzpb + hroff + ks*1024);
      bf16x8 qf = *(const bf16x8*)((const char*)hzqb + hroff + ks*1024);
      aMP = mfma16(wf[2][ks], pf, aMP);
      aAP = mfma16(wf[3][ks], pf, aAP);
      aMQ = mfma16(wf[4][ks], qf, aMQ);
      aAQ = mfma16(wf[5][ks], qf, aAQ);
    }
    float kls = 0.f;
    float z4[4];
    #pragma unroll
    for (int r=0;r<4;++r){
      float mp = aMP[r]+elf4(bpm4,r);
      float ap = aAP[r]+elf4(bps4,r);
      float mq = aMQ[r]+elf4(bqm4,r);
      float aq = aAQ[r]+elf4(bqs4,r);
      float ev = elf4(e4,r);
      float z = mq + __expf(0.5f*aq)*ev;
      float d = mq - mp;
      kls += 0.5f*(ap-aq) + 0.5f*(__expf(aq)+d*d)*__expf(-ap) - 0.5f;
      z4[r] = z;
    }
    uint2 zpk;
    zpk.x = pk_bf16(z4[0], z4[1]);
    zpk.y = pk_bf16(z4[2], z4[3]);
    *(uint2*)((char*)zbuf + hwoff) = zpk;
    if (t == ndc-1) zsel = zpk;
    kls += __shfl_xor(kls, 16);
    kls += __shfl_xor(kls, 32);
    if (lane < 16) klb[t][c][w] = kls;
    if (t < 30){
      hp4 = *(const ushort4*)(hbp + (t+2)*256);
      hq4 = *(const ushort4*)(hbp + (t+2)*256 + 128);
      e4  = *(const float4*)(ebp + (size_t)(t+2)*524288);
    }
    asm volatile("s_waitcnt lgkmcnt(0)" ::: "memory");
    __builtin_amdgcn_sched_barrier(0);
    __builtin_amdgcn_s_barrier();
    __builtin_amdgcn_sched_barrier(0);
  };

  #pragma unroll 1
  for (int t=0; t<32; t+=2){
    step(pA, qA, eA, t);
    step(pB, qB, eB, t+1);
  }

  // kls outputs (cols 130..161)
  {
    int t2 = tid>>4, c2 = tid&15;
    float s = 0.f;
    #pragma unroll
    for (int ww=0;ww<8;++ww) s += klb[t2][c2][ww];
    out[(size_t)(b0+c2)*162 + 130 + t2] = s;
  }

  // ---- fused head ----
  // deposit zsel into hzlds (k8 32..47); each thread covers (batch=c, dims j0..j0+3)
  *(uint2*)((char*)hzlds + ((32 + w*2 + (g2>>1))*16 + c)*16 + (g2&1)*8) = zsel;
  // gather h(idx) for k8 0..31 (512 pieces, one per thread)
  {
    int row = tid & 15, k8 = tid >> 4;
    int b = b0 + row;
    int idx = n_days[b] - 1;
    uint4 v = *(const uint4*)(hs + ((size_t)b*32 + idx)*256 + k8*8);
    *(uint4*)&hzlds[((size_t)k8*16 + row)*8] = v;
  }
  // head weights (wf now dead)
  bf16x8 wh[12];
  #pragma unroll
  for (int ks=0;ks<12;++ks)
    wh[ks] = *(const bf16x8*)&Wgb[(size_t)(w*16 + c)*384 + ks*32 + g2*8];
  const float4 bg4 = *(const float4*)(bg + w*16 + g2*4);
  __syncthreads();

  f32x4 acc = (f32x4){0.f,0.f,0.f,0.f};
  #pragma unroll
  for (int ks=0;ks<12;++ks){
    bf16x8 hzf = *(const bf16x8*)&hzlds[((ks*4+g2)*16 + c)*8];
    acc = mfma16(wh[ks], hzf, acc);
  }
  #pragma unroll
  for (int r=0;r<4;++r){
    float gv = tanh_s(acc[r] + elf4(bg4,r));
    glds[c*128 + w*16 + g2*4 + r] = gv;
  }
  __syncthreads();
  {
    int row = w*2 + (lane>>5);
    int ll = lane & 31;
    float s0 = 0.f, s1 = 0.f;
    #pragma unroll
    for (int e=0;e<4;++e){
      float gv = glds[row*128 + ll*4 + e];
      s0 += gv * Wy[ll*4+e];
      s1 += gv * Wy[128 + ll*4+e];
    }
    s0 += __shfl_xor(s0,1); s0 += __shfl_xor(s0,2); s0 += __shfl_xor(s0,4);
    s0 += __shfl_xor(s0,8); s0 += __shfl_xor(s0,16);
    s1 += __shfl_xor(s1,1); s1 += __shfl_xor(s1,2); s1 += __shfl_xor(s1,4);
    s1 += __shfl_xor(s1,8); s1 += __shfl_xor(s1,16);
    if (ll == 0){
      float l0 = by[0] + s0, l1 = by[1] + s1;
      float mx = fmaxf(l0,l1);
      float e0 = __expf(l0-mx), e1 = __expf(l1-mx);
      float si = e0+e1;
      ylds[row][0] = e0/si;
      ylds[row][1] = e1/si;
    }
  }
  __syncthreads();
  for (int i=tid; i<2080; i+=512){
    int row = i/130, col = i - row*130;
    float v = (col < 128) ? glds[row*128 + col] : ylds[row][col-128];
    out[(size_t)(b0+row)*162 + col] = v;
  }
}

extern "C" void kernel_launch(void* const* d_in, const int* in_sizes, int n_in,
                              void* d_out, int out_size, void* d_ws, size_t ws_size,
                              hipStream_t stream)
{
  const float* x      = (const float*)d_in[0];
  const float* y_true = (const float*)d_in[1];
  const int*   n_days = (const int*)d_in[2];
  const float* z0     = (const float*)d_in[3];
  const float* eps    = (const float*)d_in[4];
  const float* W_ih   = (const float*)d_in[5];
  const float* W_hh   = (const float*)d_in[6];
  const float* b_ih   = (const float*)d_in[7];
  const float* b_hh   = (const float*)d_in[8];
  const float* Wph    = (const float*)d_in[9];
  const float* bph    = (const float*)d_in[10];
  const float* Woh    = (const float*)d_in[11];
  const float* boh    = (const float*)d_in[12];
  const float* Wpm    = (const float*)d_in[13];
  const float* bpm    = (const float*)d_in[14];
  const float* Wps    = (const float*)d_in[15];
  const float* bps    = (const float*)d_in[16];
  const float* Wqm    = (const float*)d_in[17];
  const float* bqm    = (const float*)d_in[18];
  const float* Wqs    = (const float*)d_in[19];
  const float* bqs    = (const float*)d_in[20];
  const float* Wg     = (const float*)d_in[21];
  const float* bg     = (const float*)d_in[22];
  const float* Wy     = (const float*)d_in[23];
  const float* by     = (const float*)d_in[24];
  (void)in_sizes; (void)n_in; (void)out_size; (void)ws_size;

  u16*   wsb = (u16*)d_ws;
  float* wsf = (float*)d_ws;
  int*   wsi = (int*)d_ws;
  u16* Wih_b = wsb + 0;
  u16* Whh_b = wsb + 196608;
  u16* Wc_b  = wsb + 393216;
  u16* Wz_b  = wsb + 524288;
  u16* Wg_b  = wsb + 622592;
  float* Woy  = wsf + 335872;
  float* bpq  = wsf + 336128;
  float* bsum = wsf + 336384;
  int* perm   = wsi + 337152;
  int* nd_s   = wsi + 341248;
  int* cnt    = wsi + 345344;
  u16* xbf   = wsb + 690752;
  u16* GI    = wsb + 34245184;
  u16* hsB   = wsb + 134908480;
  u16* HPQ   = wsb + 168462912;

  hipLaunchKernelGGL(prep_all, dim3(19014), dim3(256), 0, stream,
                     x, W_ih, W_hh, Wph, Woh, Wpm, Wps, Wqm, Wqs, Wg, bph, boh,
                     b_ih, b_hh, xbf, wsb, Woy, bpq, bsum);
  hipLaunchKernelGGL(sort_days, dim3(1), dim3(1024), 0, stream,
                     n_days, perm, nd_s, cnt);
  hipLaunchKernelGGL(gemm_gi, dim3(1024,3), dim3(512), 0, stream,
                     xbf, Wih_b, bsum, perm, cnt, GI);
  hipLaunchKernelGGL(gru_seq, dim3(256), dim3(1024), 0, stream,
                     GI, Whh_b, b_hh, perm, nd_s, hsB);
  hipLaunchKernelGGL(gemm_hpq, dim3(1024), dim3(512), 0, stream,
                     xbf, hsB, Wc_b, bpq, y_true, Woy, HPQ);
  hipLaunchKernelGGL(vae_seq, dim3(256), dim3(512), 0, stream,
                     HPQ, z0, eps, n_days, Wz_b, bpm, bps, bqm, bqs,
                     hsB, Wg_b, bg, Wy, by, (float*)d_out);
}